// Round 4
// baseline (1022.452 us; speedup 1.0000x reference)
//
#include <hip/hip_runtime.h>
#include <stdint.h>
#include <stddef.h>

// Problem constants
#define TOK   4096   // B*S
#define DDIM  1024
#define EXP   8
#define HDIM  4096

typedef __bf16 bf16x8 __attribute__((ext_vector_type(8)));
typedef __bf16 bf16x4 __attribute__((ext_vector_type(4)));
typedef float  f32x4  __attribute__((ext_vector_type(4)));

// Workspace layout (all offsets 256-aligned). Total ~202 MB.
#define OFF_COUNTS 0ull
#define OFF_PREFIX 256ull
#define OFF_PERM   512ull                         // 8*4096*4  = 131072
#define OFF_WGT    (OFF_PERM + 131072ull)         // 8*4096*4  = 131072
#define OFF_XBF    (OFF_WGT + 131072ull)          // 4096*1024*2 = 8388608
#define OFF_W1T    (OFF_XBF + 8388608ull)         // 8*4096*1024*2 = 67108864
#define OFF_W2T    (OFF_W1T + 67108864ull)        // 8*1024*4096*2 = 67108864
#define OFF_HBF    (OFF_W2T + 67108864ull)        // (8192+128)*4096*2 = 68157440
#define OFF_T2E    (OFF_HBF + 68157440ull)        // 4096*16 = 65536
// Y (split-K=4 bf16 partials, 4*8192*1024*2 = 67108864 B) ALIASES OFF_W1T exactly:
// W1t is dead after gemm1; gemm2 writes Y there, combine reads it.

__device__ __forceinline__ void load16_lds(const void* g, void* l) {
  // width=16 direct global->LDS DMA; LDS dest must be wave-uniform base + lane*16
  __builtin_amdgcn_global_load_lds((__attribute__((address_space(1))) void*)g,
                                   (__attribute__((address_space(3))) void*)l,
                                   16, 0, 0);
}

// ---------------- merged prep: transpose (blocks 0..16383) + gating (blocks 16384..17407) ----
// Transpose: fp32 [E][K][N] -> bf16 [E][N][K], 64x64 tiles, float4 loads, pad-65 LDS,
// bf16x8 16B stores. Gate: fp32 logits, top-2, softmax (folds mean/8), routing lists, x->bf16.
__global__ __launch_bounds__(256) void prep_kernel(
    const float* __restrict__ W1, const float* __restrict__ W2,
    __bf16* __restrict__ W1t, __bf16* __restrict__ W2t,
    const float* __restrict__ x, const float* __restrict__ Wg,
    __bf16* __restrict__ x_bf, int* __restrict__ counts,
    int* __restrict__ perm, float* __restrict__ wgt,
    int4* __restrict__ tok2exp)
{
  __shared__ float tile[64 * 65];
  const int bid = blockIdx.x;
  const int tid = threadIdx.x;

  if (bid < 16384) {
    // ---- transpose role ----
    const int which = bid >> 13;
    const int e     = (bid >> 10) & 7;
    const int t10   = bid & 1023;
    const float* src; __bf16* dst; int Kd, Nd, tk, tn;
    if (which == 0) { Kd = 1024; Nd = 4096; src = W1; dst = W1t; tk = t10 & 15; tn = t10 >> 4; }
    else            { Kd = 4096; Nd = 1024; src = W2; dst = W2t; tk = t10 >> 4; tn = t10 & 15; }
    const int k0 = tk * 64, n0 = tn * 64;
    src += ((size_t)e * Kd + k0) * Nd + n0;
    dst += ((size_t)e * Nd + n0) * Kd + k0;

    const int lr = tid >> 4, lc = (tid & 15) * 4;
#pragma unroll
    for (int p = 0; p < 4; ++p) {
      const int r = p * 16 + lr;
      float4 v = *(const float4*)(src + (size_t)r * Nd + lc);
      tile[r * 65 + lc + 0] = v.x;
      tile[r * 65 + lc + 1] = v.y;
      tile[r * 65 + lc + 2] = v.z;
      tile[r * 65 + lc + 3] = v.w;
    }
    __syncthreads();
    const int n = tid >> 2, kcb = (tid & 3) * 8;
#pragma unroll
    for (int h = 0; h < 2; ++h) {
      const int kb = kcb + h * 32;
      bf16x8 o;
#pragma unroll
      for (int u = 0; u < 8; ++u) o[u] = (__bf16)tile[(kb + u) * 65 + n];
      *(bf16x8*)(dst + (size_t)n * Kd + kb) = o;
    }
    return;
  }

  // ---- gate role ----
  const int lane = tid & 63;
  const int wid  = tid >> 6;
  const int t    = (bid - 16384) * 4 + wid;     // one wave per token
  const float* xr = x + (size_t)t * DDIM;

  float acc[EXP];
#pragma unroll
  for (int e = 0; e < EXP; ++e) acc[e] = 0.f;

#pragma unroll
  for (int it = 0; it < 4; ++it) {
    const int d0 = it * 256 + lane * 4;
    float4 xv = *(const float4*)(xr + d0);
    bf16x4 xb = { (__bf16)xv.x, (__bf16)xv.y, (__bf16)xv.z, (__bf16)xv.w };
    *(bf16x4*)(x_bf + (size_t)t * DDIM + d0) = xb;
    const float* wrow = Wg + (size_t)d0 * EXP;
    float xs[4] = { xv.x, xv.y, xv.z, xv.w };
#pragma unroll
    for (int u = 0; u < 4; ++u) {
      float4 wa = *(const float4*)(wrow + u * 8);
      float4 wb = *(const float4*)(wrow + u * 8 + 4);
      acc[0] += xs[u] * wa.x; acc[1] += xs[u] * wa.y;
      acc[2] += xs[u] * wa.z; acc[3] += xs[u] * wa.w;
      acc[4] += xs[u] * wb.x; acc[5] += xs[u] * wb.y;
      acc[6] += xs[u] * wb.z; acc[7] += xs[u] * wb.w;
    }
  }
#pragma unroll
  for (int e = 0; e < EXP; ++e) {
    float v = acc[e];
#pragma unroll
    for (int s = 32; s > 0; s >>= 1) v += __shfl_down(v, s, 64);
    acc[e] = v;
  }
  if (lane == 0) {
    int e0 = 0; float g0 = acc[0];
#pragma unroll
    for (int e = 1; e < EXP; ++e) if (acc[e] > g0) { g0 = acc[e]; e0 = e; }
    int e1 = 0; float g1 = -3.4e38f;
#pragma unroll
    for (int e = 0; e < EXP; ++e) if (e != e0 && acc[e] > g1) { g1 = acc[e]; e1 = e; }
    float ex = __expf(g1 - g0);
    float m0 = 1.f / (1.f + ex);
    float m1 = ex  / (1.f + ex);
    int p0 = atomicAdd(&counts[e0], 1);
    perm[e0 * TOK + p0] = t;  wgt[e0 * TOK + p0] = m0 * 0.125f;
    int p1 = atomicAdd(&counts[e1], 1);
    perm[e1 * TOK + p1] = t;  wgt[e1 * TOK + p1] = m1 * 0.125f;
    tok2exp[t] = make_int4(e0, p0, e1, p1);
  }
}

__global__ void prefix_kernel(const int* __restrict__ counts, int* __restrict__ prefix)
{
  if (threadIdx.x == 0 && blockIdx.x == 0) {
    int s = 0;
    for (int e = 0; e < EXP; ++e) { prefix[e] = s; s += counts[e]; }
    prefix[EXP] = s;
  }
}

// ---------------- grouped GEMM1: h = relu(gather(x) @ W1_e + b1_e), bf16 out ----------------
// mt is the FASTEST block index: consecutive blocks share the W1t B-slab (L2 locality).
__global__ __launch_bounds__(256, 2) void gemm1_kernel(
    const __bf16* __restrict__ x_bf, const __bf16* __restrict__ W1t,
    const float* __restrict__ b1, __bf16* __restrict__ h_bf,
    const int* __restrict__ perm, const int* __restrict__ counts,
    const int* __restrict__ prefix)
{
  const int bid = blockIdx.x;
  const int e   = bid >> 10;
  const int nt  = (bid >> 5) & 31;
  const int mt  = bid & 31;
  const int cnt = counts[e];
  if (mt * 128 >= cnt) return;
  const int pfx = prefix[e];

  __shared__ __align__(16) __bf16 As[4096];
  __shared__ __align__(16) __bf16 Bs[4096];

  const int tid  = threadIdx.x;
  const int lane = tid & 63, wid = tid >> 6;
  const int wm = wid & 1, wn = wid >> 1;
  const int qd = lane >> 4, l15 = lane & 15;

  const int rA0 = tid >> 2, rA1 = rA0 + 64;
  const int pA0 = (tid & 3) ^ ((rA0 >> 1) & 3);
  const int pA1 = (tid & 3) ^ ((rA1 >> 1) & 3);
  int mA0 = mt * 128 + rA0; if (mA0 >= cnt) mA0 = cnt - 1;
  int mA1 = mt * 128 + rA1; if (mA1 >= cnt) mA1 = cnt - 1;
  const int tok0 = perm[e * TOK + mA0];
  const int tok1 = perm[e * TOK + mA1];
  const __bf16* gA0 = x_bf + (size_t)tok0 * DDIM + pA0 * 8;
  const __bf16* gA1 = x_bf + (size_t)tok1 * DDIM + pA1 * 8;
  const __bf16* Wte = W1t + (size_t)e * HDIM * DDIM;
  const __bf16* gB0 = Wte + (size_t)(nt * 128 + rA0) * DDIM + pA0 * 8;
  const __bf16* gB1 = Wte + (size_t)(nt * 128 + rA1) * DDIM + pA1 * 8;
  __bf16* ldsA0 = &As[tid * 8];
  __bf16* ldsA1 = &As[(tid + 256) * 8];
  __bf16* ldsB0 = &Bs[tid * 8];
  __bf16* ldsB1 = &Bs[(tid + 256) * 8];

  f32x4 acc[4][4] = {};

  for (int kk = 0; kk < DDIM; kk += 32) {
    __syncthreads();
    load16_lds(gA0 + kk, ldsA0);
    load16_lds(gA1 + kk, ldsA1);
    load16_lds(gB0 + kk, ldsB0);
    load16_lds(gB1 + kk, ldsB1);
    __syncthreads();
    bf16x8 af[4], bfr[4];
#pragma unroll
    for (int i = 0; i < 4; ++i) {
      int r = wm * 64 + i * 16 + l15;
      int ch = r * 4 + (qd ^ ((r >> 1) & 3));
      af[i] = *(const bf16x8*)(As + ch * 8);
    }
#pragma unroll
    for (int j = 0; j < 4; ++j) {
      int r = wn * 64 + j * 16 + l15;
      int ch = r * 4 + (qd ^ ((r >> 1) & 3));
      bfr[j] = *(const bf16x8*)(Bs + ch * 8);
    }
#pragma unroll
    for (int i = 0; i < 4; ++i)
#pragma unroll
      for (int j = 0; j < 4; ++j)
        acc[i][j] = __builtin_amdgcn_mfma_f32_16x16x32_bf16(af[i], bfr[j], acc[i][j], 0, 0, 0);
  }

  const float* b1e = b1 + (size_t)e * HDIM;
#pragma unroll
  for (int i = 0; i < 4; ++i) {
#pragma unroll
    for (int v = 0; v < 4; ++v) {
      const int rl = wm * 64 + i * 16 + qd * 4 + v;
      const int m  = mt * 128 + rl;
      if (m < cnt) {
        __bf16* hrow = h_bf + (size_t)(pfx + m) * HDIM;
#pragma unroll
        for (int j = 0; j < 4; ++j) {
          const int col = nt * 128 + wn * 64 + j * 16 + l15;
          float hv = acc[i][j][v] + b1e[col];
          hv = fmaxf(hv, 0.f);
          hrow[col] = (__bf16)hv;
        }
      }
    }
  }
}

// ---------------- grouped GEMM2 (split-K=4, bf16 partials, NO atomics) ----------------
// Y[s][gpos][col] = partial (h @ W2_e) over k-range s. mt fastest for W2t L2 locality.
// 2048 active blocks (8/CU) to hide the per-iter vmcnt drain (round-3 was 4/CU, 22% MfmaUtil).
__global__ __launch_bounds__(256, 2) void gemm2_kernel(
    const __bf16* __restrict__ h_bf, const __bf16* __restrict__ W2t,
    __bf16* __restrict__ Y,
    const int* __restrict__ counts, const int* __restrict__ prefix)
{
  const int bid = blockIdx.x;
  const int mt  = bid & 31;
  const int ks  = (bid >> 5) & 3;
  const int nt  = (bid >> 7) & 7;
  const int e   = bid >> 10;
  const int cnt = counts[e];
  if (mt * 128 >= cnt) return;
  const int pfx = prefix[e];

  __shared__ __align__(16) __bf16 As[4096];
  __shared__ __align__(16) __bf16 Bs[4096];

  const int tid  = threadIdx.x;
  const int lane = tid & 63, wid = tid >> 6;
  const int wm = wid & 1, wn = wid >> 1;
  const int qd = lane >> 4, l15 = lane & 15;

  const int rA0 = tid >> 2, rA1 = rA0 + 64;
  const int pA0 = (tid & 3) ^ ((rA0 >> 1) & 3);
  const int pA1 = (tid & 3) ^ ((rA1 >> 1) & 3);
  const __bf16* gA0 = h_bf + (size_t)(pfx + mt * 128 + rA0) * HDIM + pA0 * 8;
  const __bf16* gA1 = h_bf + (size_t)(pfx + mt * 128 + rA1) * HDIM + pA1 * 8;
  const __bf16* Wte = W2t + (size_t)e * DDIM * HDIM;
  const __bf16* gB0 = Wte + (size_t)(nt * 128 + rA0) * HDIM + pA0 * 8;
  const __bf16* gB1 = Wte + (size_t)(nt * 128 + rA1) * HDIM + pA1 * 8;
  __bf16* ldsA0 = &As[tid * 8];
  __bf16* ldsA1 = &As[(tid + 256) * 8];
  __bf16* ldsB0 = &Bs[tid * 8];
  __bf16* ldsB1 = &Bs[(tid + 256) * 8];

  f32x4 acc[4][4] = {};

  const int kbeg = ks * (HDIM / 4);
  const int kend = kbeg + (HDIM / 4);
  for (int kk = kbeg; kk < kend; kk += 32) {
    __syncthreads();
    load16_lds(gA0 + kk, ldsA0);
    load16_lds(gA1 + kk, ldsA1);
    load16_lds(gB0 + kk, ldsB0);
    load16_lds(gB1 + kk, ldsB1);
    __syncthreads();
    bf16x8 af[4], bfr[4];
#pragma unroll
    for (int i = 0; i < 4; ++i) {
      int r = wm * 64 + i * 16 + l15;
      int ch = r * 4 + (qd ^ ((r >> 1) & 3));
      af[i] = *(const bf16x8*)(As + ch * 8);
    }
#pragma unroll
    for (int j = 0; j < 4; ++j) {
      int r = wn * 64 + j * 16 + l15;
      int ch = r * 4 + (qd ^ ((r >> 1) & 3));
      bfr[j] = *(const bf16x8*)(Bs + ch * 8);
    }
#pragma unroll
    for (int i = 0; i < 4; ++i)
#pragma unroll
      for (int j = 0; j < 4; ++j)
        acc[i][j] = __builtin_amdgcn_mfma_f32_16x16x32_bf16(af[i], bfr[j], acc[i][j], 0, 0, 0);
  }

  __bf16* Ys = Y + (size_t)ks * (2 * TOK) * DDIM;
#pragma unroll
  for (int i = 0; i < 4; ++i) {
#pragma unroll
    for (int v = 0; v < 4; ++v) {
      const int rl = wm * 64 + i * 16 + qd * 4 + v;
      const int m  = mt * 128 + rl;
      if (m < cnt) {
        __bf16* yrow = Ys + (size_t)(pfx + m) * DDIM;
#pragma unroll
        for (int j = 0; j < 4; ++j) {
          const int col = nt * 128 + wn * 64 + j * 16 + l15;
          yrow[col] = (__bf16)acc[i][j][v];
        }
      }
    }
  }
}

// ---------------- combine: out[t] = sum_j w_j * (sum_s Y[s][g_j] + b2[e_j]) ----------------
__global__ __launch_bounds__(256) void combine_kernel(
    const __bf16* __restrict__ Y, const float* __restrict__ b2,
    const float* __restrict__ wgt, const int4* __restrict__ tok2exp,
    const int* __restrict__ prefix, float* __restrict__ out)
{
  const int t = blockIdx.x;
  const int c = threadIdx.x * 4;
  const int4 m = tok2exp[t];
  const int g0 = prefix[m.x] + m.y;
  const int g1 = prefix[m.z] + m.w;
  const float w0 = wgt[m.x * TOK + m.y];
  const float w1 = wgt[m.z * TOK + m.w];
  const size_t slab = (size_t)(2 * TOK) * DDIM;

  float s0x = 0.f, s0y = 0.f, s0z = 0.f, s0w = 0.f;
  float s1x = 0.f, s1y = 0.f, s1z = 0.f, s1w = 0.f;
#pragma unroll
  for (int s = 0; s < 4; ++s) {
    bf16x4 a = *(const bf16x4*)(Y + s * slab + (size_t)g0 * DDIM + c);
    bf16x4 b = *(const bf16x4*)(Y + s * slab + (size_t)g1 * DDIM + c);
    s0x += (float)a[0]; s0y += (float)a[1]; s0z += (float)a[2]; s0w += (float)a[3];
    s1x += (float)b[0]; s1y += (float)b[1]; s1z += (float)b[2]; s1w += (float)b[3];
  }
  float4 be0 = *(const float4*)(b2 + (size_t)m.x * DDIM + c);
  float4 be1 = *(const float4*)(b2 + (size_t)m.z * DDIM + c);
  float4 r;
  r.x = w0 * (s0x + be0.x) + w1 * (s1x + be1.x);
  r.y = w0 * (s0y + be0.y) + w1 * (s1y + be1.y);
  r.z = w0 * (s0z + be0.z) + w1 * (s1z + be1.z);
  r.w = w0 * (s0w + be0.w) + w1 * (s1w + be1.w);
  *(float4*)(out + (size_t)t * DDIM + c) = r;
}

extern "C" void kernel_launch(void* const* d_in, const int* in_sizes, int n_in,
                              void* d_out, int out_size, void* d_ws, size_t ws_size,
                              hipStream_t stream)
{
  const float* x  = (const float*)d_in[0];
  const float* Wg = (const float*)d_in[1];
  const float* W1 = (const float*)d_in[2];
  const float* b1 = (const float*)d_in[3];
  const float* W2 = (const float*)d_in[4];
  const float* b2 = (const float*)d_in[5];
  float* out = (float*)d_out;

  char* ws = (char*)d_ws;
  int*    counts  = (int*)(ws + OFF_COUNTS);
  int*    prefix  = (int*)(ws + OFF_PREFIX);
  int*    perm    = (int*)(ws + OFF_PERM);
  float*  wgt     = (float*)(ws + OFF_WGT);
  __bf16* x_bf    = (__bf16*)(ws + OFF_XBF);
  __bf16* W1t     = (__bf16*)(ws + OFF_W1T);
  __bf16* W2t     = (__bf16*)(ws + OFF_W2T);
  __bf16* h_bf    = (__bf16*)(ws + OFF_HBF);
  int4*   tok2exp = (int4*)(ws + OFF_T2E);
  __bf16* Y       = (__bf16*)(ws + OFF_W1T);   // aliases W1t (dead after gemm1)

  hipMemsetAsync(counts, 0, 256, stream);

  prep_kernel<<<16384 + TOK / 4, 256, 0, stream>>>(W1, W2, W1t, W2t,
                                                   x, Wg, x_bf, counts, perm, wgt, tok2exp);
  prefix_kernel<<<1, 64, 0, stream>>>(counts, prefix);
  gemm1_kernel<<<EXP * 32 * 32, 256, 0, stream>>>(x_bf, W1t, b1, h_bf, perm, counts, prefix);
  gemm2_kernel<<<EXP * 8 * 4 * 32, 256, 0, stream>>>(h_bf, W2t, Y, counts, prefix);
  combine_kernel<<<TOK, 256, 0, stream>>>(Y, b2, wgt, tok2exp, prefix, out);
}

// Round 5
// 615.982 us; speedup vs baseline: 1.6599x; 1.6599x over previous
//
#include <hip/hip_runtime.h>
#include <stdint.h>
#include <stddef.h>

// Problem constants
#define TOK   4096   // B*S
#define DDIM  1024
#define EXP   8
#define HDIM  4096

typedef __bf16 bf16x8 __attribute__((ext_vector_type(8)));
typedef __bf16 bf16x4 __attribute__((ext_vector_type(4)));
typedef float  f32x4  __attribute__((ext_vector_type(4)));

// Workspace layout (all offsets 256-aligned). Total ~202 MB.
#define OFF_COUNTS 0ull
#define OFF_PREFIX 256ull
#define OFF_PERM   512ull                         // 8*4096*4  = 131072
#define OFF_WGT    (OFF_PERM + 131072ull)         // 8*4096*4  = 131072
#define OFF_XBF    (OFF_WGT + 131072ull)          // 4096*1024*2 = 8388608
#define OFF_W1T    (OFF_XBF + 8388608ull)         // 8*4096*1024*2 = 67108864
#define OFF_W2T    (OFF_W1T + 67108864ull)        // 8*1024*4096*2 = 67108864
#define OFF_HBF    (OFF_W2T + 67108864ull)        // (8192+128)*4096*2 = 68157440
#define OFF_T2E    (OFF_HBF + 68157440ull)        // 4096*16 = 65536
// Y (split-K=4 bf16 partials, 4*8192*1024*2 = 67108864 B) ALIASES OFF_W1T exactly:
// W1t is dead after gemm1; gemm2 writes Y there, combine reads it.

__device__ __forceinline__ void load16_lds(const void* g, void* l) {
  // width=16 direct global->LDS DMA; LDS dest must be wave-uniform base + lane*16
  __builtin_amdgcn_global_load_lds((__attribute__((address_space(1))) void*)g,
                                   (__attribute__((address_space(3))) void*)l,
                                   16, 0, 0);
}

// ---------------- merged prep: transpose (blocks 0..16383) + gating (blocks 16384..17407) ----
__global__ __launch_bounds__(256) void prep_kernel(
    const float* __restrict__ W1, const float* __restrict__ W2,
    __bf16* __restrict__ W1t, __bf16* __restrict__ W2t,
    const float* __restrict__ x, const float* __restrict__ Wg,
    __bf16* __restrict__ x_bf, int* __restrict__ counts,
    int* __restrict__ perm, float* __restrict__ wgt,
    int4* __restrict__ tok2exp)
{
  __shared__ float tile[64 * 65];
  const int bid = blockIdx.x;
  const int tid = threadIdx.x;

  if (bid < 16384) {
    // ---- transpose role: fp32 [E][K][N] -> bf16 [E][N][K] ----
    const int which = bid >> 13;
    const int e     = (bid >> 10) & 7;
    const int t10   = bid & 1023;
    const float* src; __bf16* dst; int Kd, Nd, tk, tn;
    if (which == 0) { Kd = 1024; Nd = 4096; src = W1; dst = W1t; tk = t10 & 15; tn = t10 >> 4; }
    else            { Kd = 4096; Nd = 1024; src = W2; dst = W2t; tk = t10 >> 4; tn = t10 & 15; }
    const int k0 = tk * 64, n0 = tn * 64;
    src += ((size_t)e * Kd + k0) * Nd + n0;
    dst += ((size_t)e * Nd + n0) * Kd + k0;

    const int lr = tid >> 4, lc = (tid & 15) * 4;
#pragma unroll
    for (int p = 0; p < 4; ++p) {
      const int r = p * 16 + lr;
      float4 v = *(const float4*)(src + (size_t)r * Nd + lc);
      tile[r * 65 + lc + 0] = v.x;
      tile[r * 65 + lc + 1] = v.y;
      tile[r * 65 + lc + 2] = v.z;
      tile[r * 65 + lc + 3] = v.w;
    }
    __syncthreads();
    const int n = tid >> 2, kcb = (tid & 3) * 8;
#pragma unroll
    for (int h = 0; h < 2; ++h) {
      const int kb = kcb + h * 32;
      bf16x8 o;
#pragma unroll
      for (int u = 0; u < 8; ++u) o[u] = (__bf16)tile[(kb + u) * 65 + n];
      *(bf16x8*)(dst + (size_t)n * Kd + kb) = o;
    }
    return;
  }

  // ---- gate role: fp32 logits, top-2, softmax (folds mean/8), routing lists, x->bf16 ----
  const int lane = tid & 63;
  const int wid  = tid >> 6;
  const int t    = (bid - 16384) * 4 + wid;     // one wave per token
  const float* xr = x + (size_t)t * DDIM;

  float acc[EXP];
#pragma unroll
  for (int e = 0; e < EXP; ++e) acc[e] = 0.f;

#pragma unroll
  for (int it = 0; it < 4; ++it) {
    const int d0 = it * 256 + lane * 4;
    float4 xv = *(const float4*)(xr + d0);
    bf16x4 xb = { (__bf16)xv.x, (__bf16)xv.y, (__bf16)xv.z, (__bf16)xv.w };
    *(bf16x4*)(x_bf + (size_t)t * DDIM + d0) = xb;
    const float* wrow = Wg + (size_t)d0 * EXP;
    float xs[4] = { xv.x, xv.y, xv.z, xv.w };
#pragma unroll
    for (int u = 0; u < 4; ++u) {
      float4 wa = *(const float4*)(wrow + u * 8);
      float4 wb = *(const float4*)(wrow + u * 8 + 4);
      acc[0] += xs[u] * wa.x; acc[1] += xs[u] * wa.y;
      acc[2] += xs[u] * wa.z; acc[3] += xs[u] * wa.w;
      acc[4] += xs[u] * wb.x; acc[5] += xs[u] * wb.y;
      acc[6] += xs[u] * wb.z; acc[7] += xs[u] * wb.w;
    }
  }
#pragma unroll
  for (int e = 0; e < EXP; ++e) {
    float v = acc[e];
#pragma unroll
    for (int s = 32; s > 0; s >>= 1) v += __shfl_down(v, s, 64);
    acc[e] = v;
  }
  if (lane == 0) {
    int e0 = 0; float g0 = acc[0];
#pragma unroll
    for (int e = 1; e < EXP; ++e) if (acc[e] > g0) { g0 = acc[e]; e0 = e; }
    int e1 = 0; float g1 = -3.4e38f;
#pragma unroll
    for (int e = 0; e < EXP; ++e) if (e != e0 && acc[e] > g1) { g1 = acc[e]; e1 = e; }
    float ex = __expf(g1 - g0);
    float m0 = 1.f / (1.f + ex);
    float m1 = ex  / (1.f + ex);
    int p0 = atomicAdd(&counts[e0], 1);
    perm[e0 * TOK + p0] = t;  wgt[e0 * TOK + p0] = m0 * 0.125f;
    int p1 = atomicAdd(&counts[e1], 1);
    perm[e1 * TOK + p1] = t;  wgt[e1 * TOK + p1] = m1 * 0.125f;
    tok2exp[t] = make_int4(e0, p0, e1, p1);
  }
}

__global__ void prefix_kernel(const int* __restrict__ counts, int* __restrict__ prefix)
{
  if (threadIdx.x == 0 && blockIdx.x == 0) {
    int s = 0;
    for (int e = 0; e < EXP; ++e) { prefix[e] = s; s += counts[e]; }
    prefix[EXP] = s;
  }
}

// ---------------- grouped GEMM1: h = relu(gather(x) @ W1_e + b1_e), bf16 out ----------------
// Round-3 block order (e slow, mt middle, nt FAST): co-resident blocks share the gathered
// A-tile and stream W1t sequentially — round-4's mt-fastest order destroyed this (320 µs).
__global__ __launch_bounds__(256, 2) void gemm1_kernel(
    const __bf16* __restrict__ x_bf, const __bf16* __restrict__ W1t,
    const float* __restrict__ b1, __bf16* __restrict__ h_bf,
    const int* __restrict__ perm, const int* __restrict__ counts,
    const int* __restrict__ prefix)
{
  const int bid = blockIdx.x;
  const int e   = bid >> 10;
  const int mt  = (bid >> 5) & 31;
  const int nt  = bid & 31;
  const int cnt = counts[e];
  if (mt * 128 >= cnt) return;
  const int pfx = prefix[e];

  __shared__ __align__(16) __bf16 As[4096];
  __shared__ __align__(16) __bf16 Bs[4096];

  const int tid  = threadIdx.x;
  const int lane = tid & 63, wid = tid >> 6;
  const int wm = wid & 1, wn = wid >> 1;
  const int qd = lane >> 4, l15 = lane & 15;

  const int rA0 = tid >> 2, rA1 = rA0 + 64;
  const int pA0 = (tid & 3) ^ ((rA0 >> 1) & 3);
  const int pA1 = (tid & 3) ^ ((rA1 >> 1) & 3);
  int mA0 = mt * 128 + rA0; if (mA0 >= cnt) mA0 = cnt - 1;
  int mA1 = mt * 128 + rA1; if (mA1 >= cnt) mA1 = cnt - 1;
  const int tok0 = perm[e * TOK + mA0];
  const int tok1 = perm[e * TOK + mA1];
  const __bf16* gA0 = x_bf + (size_t)tok0 * DDIM + pA0 * 8;
  const __bf16* gA1 = x_bf + (size_t)tok1 * DDIM + pA1 * 8;
  const __bf16* Wte = W1t + (size_t)e * HDIM * DDIM;
  const __bf16* gB0 = Wte + (size_t)(nt * 128 + rA0) * DDIM + pA0 * 8;
  const __bf16* gB1 = Wte + (size_t)(nt * 128 + rA1) * DDIM + pA1 * 8;
  __bf16* ldsA0 = &As[tid * 8];
  __bf16* ldsA1 = &As[(tid + 256) * 8];
  __bf16* ldsB0 = &Bs[tid * 8];
  __bf16* ldsB1 = &Bs[(tid + 256) * 8];

  f32x4 acc[4][4] = {};

  for (int kk = 0; kk < DDIM; kk += 32) {
    __syncthreads();
    load16_lds(gA0 + kk, ldsA0);
    load16_lds(gA1 + kk, ldsA1);
    load16_lds(gB0 + kk, ldsB0);
    load16_lds(gB1 + kk, ldsB1);
    __syncthreads();
    bf16x8 af[4], bfr[4];
#pragma unroll
    for (int i = 0; i < 4; ++i) {
      int r = wm * 64 + i * 16 + l15;
      int ch = r * 4 + (qd ^ ((r >> 1) & 3));
      af[i] = *(const bf16x8*)(As + ch * 8);
    }
#pragma unroll
    for (int j = 0; j < 4; ++j) {
      int r = wn * 64 + j * 16 + l15;
      int ch = r * 4 + (qd ^ ((r >> 1) & 3));
      bfr[j] = *(const bf16x8*)(Bs + ch * 8);
    }
#pragma unroll
    for (int i = 0; i < 4; ++i)
#pragma unroll
      for (int j = 0; j < 4; ++j)
        acc[i][j] = __builtin_amdgcn_mfma_f32_16x16x32_bf16(af[i], bfr[j], acc[i][j], 0, 0, 0);
  }

  const float* b1e = b1 + (size_t)e * HDIM;
#pragma unroll
  for (int i = 0; i < 4; ++i) {
#pragma unroll
    for (int v = 0; v < 4; ++v) {
      const int rl = wm * 64 + i * 16 + qd * 4 + v;
      const int m  = mt * 128 + rl;
      if (m < cnt) {
        __bf16* hrow = h_bf + (size_t)(pfx + m) * HDIM;
#pragma unroll
        for (int j = 0; j < 4; ++j) {
          const int col = nt * 128 + wn * 64 + j * 16 + l15;
          float hv = acc[i][j][v] + b1e[col];
          hv = fmaxf(hv, 0.f);
          hrow[col] = (__bf16)hv;
        }
      }
    }
  }
}

// ---------------- grouped GEMM2 (split-K=4, bf16 partials, NO atomics) ----------------
// Round-3 block order (e slow, mt, nt, ks FAST) + split-K=4: 2048 active blocks (8/CU)
// to hide the per-iter vmcnt drain (round-3 split-2 was 4/CU, MfmaUtil capped at 22%).
__global__ __launch_bounds__(256, 2) void gemm2_kernel(
    const __bf16* __restrict__ h_bf, const __bf16* __restrict__ W2t,
    __bf16* __restrict__ Y,
    const int* __restrict__ counts, const int* __restrict__ prefix)
{
  const int bid = blockIdx.x;
  const int ks  = bid & 3;
  const int nt  = (bid >> 2) & 7;
  const int mt  = (bid >> 5) & 31;
  const int e   = bid >> 10;
  const int cnt = counts[e];
  if (mt * 128 >= cnt) return;
  const int pfx = prefix[e];

  __shared__ __align__(16) __bf16 As[4096];
  __shared__ __align__(16) __bf16 Bs[4096];

  const int tid  = threadIdx.x;
  const int lane = tid & 63, wid = tid >> 6;
  const int wm = wid & 1, wn = wid >> 1;
  const int qd = lane >> 4, l15 = lane & 15;

  const int rA0 = tid >> 2, rA1 = rA0 + 64;
  const int pA0 = (tid & 3) ^ ((rA0 >> 1) & 3);
  const int pA1 = (tid & 3) ^ ((rA1 >> 1) & 3);
  const __bf16* gA0 = h_bf + (size_t)(pfx + mt * 128 + rA0) * HDIM + pA0 * 8;
  const __bf16* gA1 = h_bf + (size_t)(pfx + mt * 128 + rA1) * HDIM + pA1 * 8;
  const __bf16* Wte = W2t + (size_t)e * DDIM * HDIM;
  const __bf16* gB0 = Wte + (size_t)(nt * 128 + rA0) * HDIM + pA0 * 8;
  const __bf16* gB1 = Wte + (size_t)(nt * 128 + rA1) * HDIM + pA1 * 8;
  __bf16* ldsA0 = &As[tid * 8];
  __bf16* ldsA1 = &As[(tid + 256) * 8];
  __bf16* ldsB0 = &Bs[tid * 8];
  __bf16* ldsB1 = &Bs[(tid + 256) * 8];

  f32x4 acc[4][4] = {};

  const int kbeg = ks * (HDIM / 4);
  const int kend = kbeg + (HDIM / 4);
  for (int kk = kbeg; kk < kend; kk += 32) {
    __syncthreads();
    load16_lds(gA0 + kk, ldsA0);
    load16_lds(gA1 + kk, ldsA1);
    load16_lds(gB0 + kk, ldsB0);
    load16_lds(gB1 + kk, ldsB1);
    __syncthreads();
    bf16x8 af[4], bfr[4];
#pragma unroll
    for (int i = 0; i < 4; ++i) {
      int r = wm * 64 + i * 16 + l15;
      int ch = r * 4 + (qd ^ ((r >> 1) & 3));
      af[i] = *(const bf16x8*)(As + ch * 8);
    }
#pragma unroll
    for (int j = 0; j < 4; ++j) {
      int r = wn * 64 + j * 16 + l15;
      int ch = r * 4 + (qd ^ ((r >> 1) & 3));
      bfr[j] = *(const bf16x8*)(Bs + ch * 8);
    }
#pragma unroll
    for (int i = 0; i < 4; ++i)
#pragma unroll
      for (int j = 0; j < 4; ++j)
        acc[i][j] = __builtin_amdgcn_mfma_f32_16x16x32_bf16(af[i], bfr[j], acc[i][j], 0, 0, 0);
  }

  __bf16* Ys = Y + (size_t)ks * (2 * TOK) * DDIM;
#pragma unroll
  for (int i = 0; i < 4; ++i) {
#pragma unroll
    for (int v = 0; v < 4; ++v) {
      const int rl = wm * 64 + i * 16 + qd * 4 + v;
      const int m  = mt * 128 + rl;
      if (m < cnt) {
        __bf16* yrow = Ys + (size_t)(pfx + m) * DDIM;
#pragma unroll
        for (int j = 0; j < 4; ++j) {
          const int col = nt * 128 + wn * 64 + j * 16 + l15;
          yrow[col] = (__bf16)acc[i][j][v];
        }
      }
    }
  }
}

// ---------------- combine: out[t] = sum_j w_j * (sum_s Y[s][g_j] + b2[e_j]) ----------------
__global__ __launch_bounds__(256) void combine_kernel(
    const __bf16* __restrict__ Y, const float* __restrict__ b2,
    const float* __restrict__ wgt, const int4* __restrict__ tok2exp,
    const int* __restrict__ prefix, float* __restrict__ out)
{
  const int t = blockIdx.x;
  const int c = threadIdx.x * 4;
  const int4 m = tok2exp[t];
  const int g0 = prefix[m.x] + m.y;
  const int g1 = prefix[m.z] + m.w;
  const float w0 = wgt[m.x * TOK + m.y];
  const float w1 = wgt[m.z * TOK + m.w];
  const size_t slab = (size_t)(2 * TOK) * DDIM;

  float s0x = 0.f, s0y = 0.f, s0z = 0.f, s0w = 0.f;
  float s1x = 0.f, s1y = 0.f, s1z = 0.f, s1w = 0.f;
#pragma unroll
  for (int s = 0; s < 4; ++s) {
    bf16x4 a = *(const bf16x4*)(Y + s * slab + (size_t)g0 * DDIM + c);
    bf16x4 b = *(const bf16x4*)(Y + s * slab + (size_t)g1 * DDIM + c);
    s0x += (float)a[0]; s0y += (float)a[1]; s0z += (float)a[2]; s0w += (float)a[3];
    s1x += (float)b[0]; s1y += (float)b[1]; s1z += (float)b[2]; s1w += (float)b[3];
  }
  float4 be0 = *(const float4*)(b2 + (size_t)m.x * DDIM + c);
  float4 be1 = *(const float4*)(b2 + (size_t)m.z * DDIM + c);
  float4 r;
  r.x = w0 * (s0x + be0.x) + w1 * (s1x + be1.x);
  r.y = w0 * (s0y + be0.y) + w1 * (s1y + be1.y);
  r.z = w0 * (s0z + be0.z) + w1 * (s1z + be1.z);
  r.w = w0 * (s0w + be0.w) + w1 * (s1w + be1.w);
  *(float4*)(out + (size_t)t * DDIM + c) = r;
}

extern "C" void kernel_launch(void* const* d_in, const int* in_sizes, int n_in,
                              void* d_out, int out_size, void* d_ws, size_t ws_size,
                              hipStream_t stream)
{
  const float* x  = (const float*)d_in[0];
  const float* Wg = (const float*)d_in[1];
  const float* W1 = (const float*)d_in[2];
  const float* b1 = (const float*)d_in[3];
  const float* W2 = (const float*)d_in[4];
  const float* b2 = (const float*)d_in[5];
  float* out = (float*)d_out;

  char* ws = (char*)d_ws;
  int*    counts  = (int*)(ws + OFF_COUNTS);
  int*    prefix  = (int*)(ws + OFF_PREFIX);
  int*    perm    = (int*)(ws + OFF_PERM);
  float*  wgt     = (float*)(ws + OFF_WGT);
  __bf16* x_bf    = (__bf16*)(ws + OFF_XBF);
  __bf16* W1t     = (__bf16*)(ws + OFF_W1T);
  __bf16* W2t     = (__bf16*)(ws + OFF_W2T);
  __bf16* h_bf    = (__bf16*)(ws + OFF_HBF);
  int4*   tok2exp = (int4*)(ws + OFF_T2E);
  __bf16* Y       = (__bf16*)(ws + OFF_W1T);   // aliases W1t (dead after gemm1)

  hipMemsetAsync(counts, 0, 256, stream);

  prep_kernel<<<16384 + TOK / 4, 256, 0, stream>>>(W1, W2, W1t, W2t,
                                                   x, Wg, x_bf, counts, perm, wgt, tok2exp);
  prefix_kernel<<<1, 64, 0, stream>>>(counts, prefix);
  gemm1_kernel<<<EXP * 32 * 32, 256, 0, stream>>>(x_bf, W1t, b1, h_bf, perm, counts, prefix);
  gemm2_kernel<<<EXP * 32 * 8 * 4, 256, 0, stream>>>(h_bf, W2t, Y, counts, prefix);
  combine_kernel<<<TOK, 256, 0, stream>>>(Y, b2, wgt, tok2exp, prefix, out);
}